// Round 10
// baseline (4498.217 us; speedup 1.0000x reference)
//
#include <hip/hip_runtime.h>

// Stacked LSTM, fp32 semantics via bf16x3 split-precision MFMA. B=T=512.
//
// R10: abandon the VALU path (asymptote ~1300us; MfmaUtil was 0.0 all
// session) and use the matrix pipe. z = W@x with W = Wh+Wl, x = xh+xl
// (bf16 RNE splits): z ~= Wh*xh + Wh*xl + Wl*xh, each product EXACT in
// fp32 MFMA accumulation; dropped Wl*xl ~ 2^-18 relative -> ~4e-6 abs
// per gate per step, damped by contractive LSTM gates; threshold 4.4e-4.
//
// - 32 blocks x 16 batch rows (M=16 MFMA tile), 8 waves each.
// - wave w owns N-tiles {w, 8+w, ...}; B-frags (weights, bf16 hi/lo) live
//   in registers/AGPRs -- MFMA reads AGPRs natively, so the allocator's
//   AGPR placement (which killed the VALU path) is FREE here.
// - concat(h,x) as bf16 hi/lo planes in LDS [2][16][KP+8] (pad: 2-way max).
// - z [4U x 16] fp32 in LDS (col-major, stride 20: conflict-free b128).
// - cell: 4U threads, thread = (unit u, 4 rows), coalesced h stores as
//   packed u32 (hi|lo<<16) -> next layer re-splits. 2 barriers/step.
// - fragment layouts (gfx950 16x16x32 bf16): A row=lane%16, k=8*(lane/16)+j;
//   B col=lane%16, k=8*(lane/16)+j; D col=lane%16, row=4*(lane/16)+reg.

#define T_SEQ 512
#define B_TOT 512

typedef __attribute__((ext_vector_type(8))) short short8;   // 8 bf16
typedef __attribute__((ext_vector_type(4))) float f32x4;

__device__ __forceinline__ unsigned short bf16_rne(float f) {
    unsigned u = __float_as_uint(f);
    u += 0x7FFFu + ((u >> 16) & 1u);
    return (unsigned short)(u >> 16);
}
__device__ __forceinline__ float bf16_to_f(unsigned short h) {
    return __uint_as_float(((unsigned)h) << 16);
}
__device__ __forceinline__ float sigmoidf_(float x) {
    return 1.0f / (1.0f + __expf(-x));
}
__device__ __forceinline__ float tanh_fast(float x) {
    float e = __expf(2.0f * x);
    return 1.0f - 2.0f / (1.0f + e);
}

// U: units. FI: input feats. KT: K-tiles of 32. SLOTS: max N-tiles/wave.
// XF32: input is raw fp32 (layer 0); else packed u32 bf16-pairs.
template<int U, int FI, int KT, int SLOTS, bool XF32, bool SEQ, bool FINAL>
__global__ __launch_bounds__(512, 1)
void lstm_mfma(const float* __restrict__ Xf, const unsigned* __restrict__ Xpk,
               const float* __restrict__ W,  const float* __restrict__ Bv,
               unsigned* __restrict__ Hpk,
               const float* __restrict__ Wd, const float* __restrict__ bd,
               float* __restrict__ OUT)
{
    constexpr int DIN = U + FI;
    constexpr int G   = 4 * U;
    constexpr int KP  = KT * 32;
    static_assert(KP >= DIN, "K padding must cover DIN");
    constexpr int KPP = KP + 8;               // row pad: 2-way banks max
    constexpr int NT  = (G + 15) / 16;        // N-tiles
    constexpr int CT  = 4 * U;                // cell threads
    constexpr int XIT = (16 * FI + 511) / 512;
    static_assert(SLOTS * 8 >= NT, "slots must cover tiles");

    __shared__ unsigned short Abuf[2][16][KPP];   // [plane hi/lo][row][k]
    __shared__ float zbuf[NT * 16][20];           // [gate col][row(16)+pad]

    const int tid  = threadIdx.x;
    const int wid  = tid >> 6;
    const int l15  = tid & 15;          // lane % 16
    const int l4   = (tid >> 4) & 3;    // lane / 16
    const int brow = blockIdx.x * 16;

    // ---- weight fragments (bf16 hi/lo) -> regs/AGPRs, loaded once ----
    short8 Bh[SLOTS][KT], Bl[SLOTS][KT];
    #pragma unroll
    for (int s2 = 0; s2 < SLOTS; ++s2) {
        const int nt  = s2 * 8 + wid;
        const int col = nt * 16 + l15;
        #pragma unroll
        for (int kt = 0; kt < KT; ++kt) {
            #pragma unroll
            for (int j = 0; j < 8; ++j) {
                const int k = kt * 32 + l4 * 8 + j;
                const float wv = (nt < NT && col < G && k < DIN)
                               ? W[(size_t)k * G + col] : 0.0f;
                const unsigned short hh = bf16_rne(wv);
                const unsigned short ll = bf16_rne(wv - bf16_to_f(hh));
                Bh[s2][kt][j] = (short)hh;
                Bl[s2][kt][j] = (short)ll;
            }
        }
    }

    // ---- cell-thread constants: thread = (unit cu, row group rg) ----
    const int cu = (tid < CT) ? (tid % U) : 0;
    const int rg = (tid < CT) ? (tid / U) : 0;
    float bia[4] = {0.f, 0.f, 0.f, 0.f};
    if (tid < CT) {
        bia[0] = Bv[cu]; bia[1] = Bv[U + cu];
        bia[2] = Bv[2 * U + cu]; bia[3] = Bv[3 * U + cu];
    }
    float c_[4] = {0.f, 0.f, 0.f, 0.f}, h_[4] = {0.f, 0.f, 0.f, 0.f};
    float wdv = 0.0f;
    if constexpr (FINAL) { if (tid < CT) wdv = Wd[cu]; }

    // ---- x-stage mapping ----
    const int xrow = tid >> 5;               // XF32: 16 rows x 32 thr
    const int xj   = (tid & 31) * 2;         // XF32: 2 floats/thread (FI=64)
    size_t xfbase = 0;
    if constexpr (XF32) xfbase = ((size_t)(brow + xrow) * T_SEQ) * FI + xj;
    int   xrows[XIT], xjs[XIT];
    size_t xbase[XIT];
    bool  xok[XIT];
    if constexpr (!XF32) {
        #pragma unroll
        for (int it = 0; it < XIT; ++it) {
            const int idx = it * 512 + tid;
            xok[it]   = (idx < 16 * FI);
            const int r = xok[it] ? (idx / FI) : 0;
            const int j = xok[it] ? (idx % FI) : 0;
            xrows[it] = r; xjs[it] = j;
            xbase[it] = ((size_t)(brow + r) * T_SEQ) * FI + j;
        }
    }

    // ---- init: zero A planes (h=0 + k-pad), stage x(0) ----
    for (int i = tid; i < 2 * 16 * KPP; i += 512)
        ((unsigned short*)Abuf)[i] = 0;
    __syncthreads();
    if constexpr (XF32) {
        const float2 xv = *(const float2*)&Xf[xfbase];   // t = 0
        const unsigned short h0 = bf16_rne(xv.x), h1 = bf16_rne(xv.y);
        Abuf[0][xrow][U + xj]     = h0;
        Abuf[0][xrow][U + xj + 1] = h1;
        Abuf[1][xrow][U + xj]     = bf16_rne(xv.x - bf16_to_f(h0));
        Abuf[1][xrow][U + xj + 1] = bf16_rne(xv.y - bf16_to_f(h1));
    } else {
        #pragma unroll
        for (int it = 0; it < XIT; ++it) if (xok[it]) {
            const unsigned v = Xpk[xbase[it]];           // t = 0
            Abuf[0][xrows[it]][U + xjs[it]] = (unsigned short)(v & 0xffffu);
            Abuf[1][xrows[it]][U + xjs[it]] = (unsigned short)(v >> 16);
        }
    }
    __syncthreads();

    for (int t = 0; t < T_SEQ; ++t) {
        const bool dopre = (t + 1 < T_SEQ);

        // prefetch x(t+1) global->reg (retires under the MFMAs)
        float2 xv;
        unsigned xg[XIT];
        if constexpr (XF32) {
            if (dopre) xv = *(const float2*)&Xf[xfbase + (size_t)(t + 1) * FI];
        } else {
            #pragma unroll
            for (int it = 0; it < XIT; ++it)
                if (dopre && xok[it]) xg[it] = Xpk[xbase[it] + (size_t)(t + 1) * FI];
        }

        // ---- GEMM: z = concat(h,x) @ W, bf16x3, A streamed per K-tile ----
        f32x4 acc[SLOTS];
        #pragma unroll
        for (int s2 = 0; s2 < SLOTS; ++s2) acc[s2] = (f32x4){0.f, 0.f, 0.f, 0.f};
        #pragma unroll
        for (int kt = 0; kt < KT; ++kt) {
            const short8 Ah = *(const short8*)&Abuf[0][l15][kt * 32 + l4 * 8];
            const short8 Al = *(const short8*)&Abuf[1][l15][kt * 32 + l4 * 8];
            #pragma unroll
            for (int s2 = 0; s2 < SLOTS; ++s2)
                acc[s2] = __builtin_amdgcn_mfma_f32_16x16x32_bf16(Ah, Bh[s2][kt], acc[s2], 0, 0, 0);
            #pragma unroll
            for (int s2 = 0; s2 < SLOTS; ++s2)
                acc[s2] = __builtin_amdgcn_mfma_f32_16x16x32_bf16(Al, Bh[s2][kt], acc[s2], 0, 0, 0);
            #pragma unroll
            for (int s2 = 0; s2 < SLOTS; ++s2)
                acc[s2] = __builtin_amdgcn_mfma_f32_16x16x32_bf16(Ah, Bl[s2][kt], acc[s2], 0, 0, 0);
        }
        #pragma unroll
        for (int s2 = 0; s2 < SLOTS; ++s2) {
            const int nt = s2 * 8 + wid;
            if (nt < NT)
                *(f32x4*)&zbuf[nt * 16 + l15][l4 * 4] = acc[s2];
        }
        __syncthreads();

        // ---- cell update: thread (cu, rows rg*4..rg*4+3) ----
        if (tid < CT) {
            const f32x4 zf = *(const f32x4*)&zbuf[0 * U + cu][rg * 4];
            const f32x4 zi = *(const f32x4*)&zbuf[1 * U + cu][rg * 4];
            const f32x4 zg = *(const f32x4*)&zbuf[2 * U + cu][rg * 4];
            const f32x4 zo = *(const f32x4*)&zbuf[3 * U + cu][rg * 4];
            #pragma unroll
            for (int r = 0; r < 4; ++r) {
                const float F  = sigmoidf_(zf[r] + bia[0]);
                const float I  = sigmoidf_(zi[r] + bia[1]);
                const float Gv = tanh_fast(zg[r] + bia[2]);
                const float O  = sigmoidf_(zo[r] + bia[3]);
                c_[r] = F * c_[r] + I * Gv;
                h_[r] = O * tanh_fast(c_[r]);
                const int row = rg * 4 + r;
                const unsigned short hh = bf16_rne(h_[r]);
                const unsigned short hl = bf16_rne(h_[r] - bf16_to_f(hh));
                Abuf[0][row][cu] = hh;
                Abuf[1][row][cu] = hl;
                if constexpr (SEQ)
                    Hpk[((size_t)(brow + row) * T_SEQ + t) * U + cu]
                        = (unsigned)hh | ((unsigned)hl << 16);
            }
        }
        // ---- write staged x(t+1) (disjoint k-range from h writes) ----
        if (dopre) {
            if constexpr (XF32) {
                const unsigned short h0 = bf16_rne(xv.x), h1 = bf16_rne(xv.y);
                Abuf[0][xrow][U + xj]     = h0;
                Abuf[0][xrow][U + xj + 1] = h1;
                Abuf[1][xrow][U + xj]     = bf16_rne(xv.x - bf16_to_f(h0));
                Abuf[1][xrow][U + xj + 1] = bf16_rne(xv.y - bf16_to_f(h1));
            } else {
                #pragma unroll
                for (int it = 0; it < XIT; ++it) if (xok[it]) {
                    Abuf[0][xrows[it]][U + xjs[it]] = (unsigned short)(xg[it] & 0xffffu);
                    Abuf[1][xrows[it]][U + xjs[it]] = (unsigned short)(xg[it] >> 16);
                }
            }
        }
        __syncthreads();
    }

    if constexpr (FINAL) {
        // dense head: OUT[row] = sum_u h[row][u] * Wd[u] + bd
        if (tid < CT) {
            #pragma unroll
            for (int r = 0; r < 4; ++r)
                zbuf[cu][rg * 4 + r] = h_[r] * wdv;
        }
        __syncthreads();
        if (tid < 16) {
            float a2 = bd[0];
            for (int u = 0; u < U; ++u) a2 += zbuf[u][tid];
            OUT[brow + tid] = a2;
        }
    }
}

extern "C" void kernel_launch(void* const* d_in, const int* in_sizes, int n_in,
                              void* d_out, int out_size, void* d_ws, size_t ws_size,
                              hipStream_t stream)
{
    const float* x    = (const float*)d_in[0];
    const float* W0   = (const float*)d_in[1];
    const float* b0   = (const float*)d_in[2];
    const float* W1   = (const float*)d_in[3];
    const float* b1   = (const float*)d_in[4];
    const float* W2   = (const float*)d_in[5];
    const float* b2   = (const float*)d_in[6];
    const float* W3   = (const float*)d_in[7];
    const float* b3   = (const float*)d_in[8];
    const float* Wout = (const float*)d_in[9];
    const float* bout = (const float*)d_in[10];
    float* out = (float*)d_out;

    // packed bf16-pair (u32) hidden sequences: same 4B/elem footprint as
    // the fp32 layout of earlier rounds (peak 189MB, known to fit d_ws).
    unsigned* H0pk = (unsigned*)d_ws;                          // 512*512*100
    unsigned* H1pk = H0pk + (size_t)B_TOT * T_SEQ * 100;       // 512*512*80
    unsigned* H2pk = (unsigned*)d_ws;                          // reuse H0 slot

    const dim3 grid(B_TOT / 16);   // 32 blocks x 16 rows
    const dim3 blk(512);

    // <U, FI, KT, SLOTS, XF32, SEQ, FINAL>
    hipLaunchKernelGGL((lstm_mfma<100,  64, 6, 4, true,  true,  false>),
                       grid, blk, 0, stream,
                       x, nullptr, W0, b0, H0pk, nullptr, nullptr, nullptr);
    hipLaunchKernelGGL((lstm_mfma< 80, 100, 6, 3, false, true,  false>),
                       grid, blk, 0, stream,
                       nullptr, H0pk, W1, b1, H1pk, nullptr, nullptr, nullptr);
    hipLaunchKernelGGL((lstm_mfma< 50,  80, 5, 2, false, true,  false>),
                       grid, blk, 0, stream,
                       nullptr, H1pk, W2, b2, H2pk, nullptr, nullptr, nullptr);
    hipLaunchKernelGGL((lstm_mfma< 30,  50, 3, 1, false, false, true >),
                       grid, blk, 0, stream,
                       nullptr, H2pk, W3, b3, nullptr, Wout, bout, out);
}

// Round 11
// 3806.116 us; speedup vs baseline: 1.1818x; 1.1818x over previous
//
#include <hip/hip_runtime.h>

// Stacked LSTM (100/80/50/30) + dense head, fp32 semantics via bf16x3 MFMA.
//
// R11 (from R10 post-mortem):
//  - OPERAND SWAP: A = W^T tile (M=16 gate-cols), B = act (K x 16 rows).
//    Gate columns PERMUTED so tile = 4 units x 4 gates (col = 4*ui + gate):
//    D-frag then hands each lane all 4 gate-z for one (unit,row) in its 4
//    acc regs -> cell update lane-local: no zbuf, no cell phase, no second
//    barrier. ONE __syncthreads per step.
//  - Weights (bf16 hi/lo frags) pinned to AGPRs via asm "+a": MFMA reads
//    A from AGPRs natively (only VALU can't, R6). L0: 192 AGPR + ~60 VGPR
//    fits the 256/wave unified budget at 8 waves.
//  - act LDS rows: stride_dw = 4*(4KT+1) (4*odd) -> ds_read_b128 at the
//    8-cycle data floor, no extra conflicts. Bias from a broadcast LDS
//    table, folded into acc init.
//  - bf16x3: z = Wh*ah + Wl*ah + Wh*al (dropped Wl*al ~ 2^-18) - numerics
//    proven in R10 (absmax 7.6e-6 vs 4.4e-4 threshold).

#define T_SEQ 512
#define B_TOT 512

typedef __attribute__((ext_vector_type(8))) short short8;   // 8 bf16
typedef __attribute__((ext_vector_type(4))) float f32x4;

__device__ __forceinline__ unsigned short bf16_rne(float f) {
    unsigned u = __float_as_uint(f);
    u += 0x7FFFu + ((u >> 16) & 1u);
    return (unsigned short)(u >> 16);
}
__device__ __forceinline__ float bf16_to_f(unsigned short h) {
    return __uint_as_float(((unsigned)h) << 16);
}
__device__ __forceinline__ float sigmoidf_(float x) {
    return 1.0f / (1.0f + __expf(-x));
}
__device__ __forceinline__ float tanh_fast(float x) {
    float e = __expf(2.0f * x);
    return 1.0f - 2.0f / (1.0f + e);
}

// U: real units, UP: units padded to mult of 4, FI: input feats,
// KT: K-tiles of 32, SLOTS: weight slots per wave (tiles = wid + 8*s).
template<int U, int UP, int FI, int KT, int SLOTS, bool XF32, bool SEQ, bool FINAL>
__global__ __launch_bounds__(512, 1)
void lstm_mfma(const float* __restrict__ Xf, const unsigned* __restrict__ Xpk,
               const float* __restrict__ W,  const float* __restrict__ Bv,
               unsigned* __restrict__ Hpk,
               const float* __restrict__ Wd, const float* __restrict__ bd,
               float* __restrict__ OUT)
{
    constexpr int DIN  = U + FI;
    constexpr int G    = 4 * U;
    constexpr int NT   = UP / 4;              // 16-col tiles (4 units each)
    constexpr int KP   = KT * 32;
    static_assert(KP >= DIN, "K padding must cover DIN");
    constexpr int KPPS = KT * 32 + 8;         // row stride (shorts): dw = 4*(4KT+1)
    constexpr int XIT  = XF32 ? 1 : (16 * FI + 511) / 512;
    static_assert(8 * SLOTS >= NT, "slots must cover tiles");

    __shared__ __align__(16) short Abuf[2][2][16][KPPS];  // [buf][plane][row][k]
    __shared__ __align__(16) f32x4 btab[NT * 4];          // bias per unit-slot
    __shared__ float redu[8][16];                         // FINAL reduce

    const int tid  = threadIdx.x;
    const int wid  = tid >> 6;
    const int l15  = tid & 15;          // n-index: batch row / A m-index
    const int l4   = (tid >> 4) & 3;    // k-slice / unit-within-tile
    const int brow = blockIdx.x * 16;

    // ---- weight fragments (bf16 hi/lo), permuted cols, pinned to AGPR ----
    short8 Wh[SLOTS][KT], Wl[SLOTS][KT];
    #pragma unroll
    for (int s = 0; s < SLOTS; ++s) {
        const int ti = wid + 8 * s;
        #pragma unroll
        for (int kt = 0; kt < KT; ++kt) {
            short8 hh, ll;
            #pragma unroll
            for (int j = 0; j < 8; ++j) {
                const int k    = kt * 32 + l4 * 8 + j;
                const int up   = ti * 4 + (l15 >> 2);    // unit
                const int gate = l15 & 3;
                float v = 0.0f;
                if (ti < NT && up < U && k < DIN)
                    v = W[(size_t)k * G + gate * U + up];
                const unsigned short hb = bf16_rne(v);
                hh[j] = (short)hb;
                ll[j] = (short)bf16_rne(v - bf16_to_f(hb));
            }
            Wh[s][kt] = hh; Wl[s][kt] = ll;
            asm("" : "+a"(Wh[s][kt]));   // keep in AGPR file (MFMA reads it there)
            asm("" : "+a"(Wl[s][kt]));
        }
    }

    // ---- bias table: btab[u'] = {Bv[g*U+u'] g=0..3}, 0 for padded units ----
    if (tid < NT * 4) {
        f32x4 b = {0.f, 0.f, 0.f, 0.f};
        if (tid < U) { b[0]=Bv[tid]; b[1]=Bv[U+tid]; b[2]=Bv[2*U+tid]; b[3]=Bv[3*U+tid]; }
        btab[tid] = b;
    }

    // ---- x staging maps ----
    const int xrow = tid >> 5;              // XF32: 32 thr/row, 2 floats each
    const int xj   = (tid & 31) * 2;
    size_t xfb = 0;
    if constexpr (XF32) xfb = ((size_t)(brow + xrow) * T_SEQ) * FI + xj;
    int  xoff[XIT], xwr[XIT], xwc[XIT];
    bool xok[XIT];
    if constexpr (!XF32) {
        #pragma unroll
        for (int it = 0; it < XIT; ++it) {
            const int idx = it * 512 + tid;
            xok[it] = (idx < 16 * FI);
            const int r = xok[it] ? (idx / FI) : 0;
            const int j = xok[it] ? (idx % FI) : 0;
            xwr[it] = r; xwc[it] = j;
            xoff[it] = (brow + r) * T_SEQ * FI + j;
        }
    }

    // ---- init: zero act buffers (h=0 + pads), stage x(0) ----
    for (int i = tid; i < 2 * 2 * 16 * KPPS; i += 512) ((short*)Abuf)[i] = 0;
    __syncthreads();
    if constexpr (XF32) {
        const float2 xv = *(const float2*)&Xf[xfb];
        const unsigned short h0 = bf16_rne(xv.x), h1 = bf16_rne(xv.y);
        Abuf[0][0][xrow][U + xj]     = (short)h0;
        Abuf[0][0][xrow][U + xj + 1] = (short)h1;
        Abuf[0][1][xrow][U + xj]     = (short)bf16_rne(xv.x - bf16_to_f(h0));
        Abuf[0][1][xrow][U + xj + 1] = (short)bf16_rne(xv.y - bf16_to_f(h1));
    } else {
        #pragma unroll
        for (int it = 0; it < XIT; ++it) if (xok[it]) {
            const unsigned v = Xpk[xoff[it]];
            Abuf[0][0][xwr[it]][U + xwc[it]] = (short)(v & 0xffffu);
            Abuf[0][1][xwr[it]][U + xwc[it]] = (short)(v >> 16);
        }
    }
    __syncthreads();

    float c_[SLOTS], hlast[SLOTS];
    #pragma unroll
    for (int s = 0; s < SLOTS; ++s) { c_[s] = 0.0f; hlast[s] = 0.0f; }

    for (int t = 0; t < T_SEQ; ++t) {
        const int cur = t & 1, nxt = cur ^ 1;
        const bool dopre = (t + 1 < T_SEQ);

        // prefetch x(t+1) global->reg (retires under the MFMAs)
        float2 xv;
        unsigned xg[XIT];
        if constexpr (XF32) {
            if (dopre) xv = *(const float2*)&Xf[xfb + (size_t)(t + 1) * FI];
        } else {
            #pragma unroll
            for (int it = 0; it < XIT; ++it)
                if (dopre && xok[it]) xg[it] = Xpk[xoff[it] + (t + 1) * FI];
        }

        // ---- acc init = bias (broadcast LDS read) ----
        f32x4 acc[SLOTS];
        #pragma unroll
        for (int s = 0; s < SLOTS; ++s) {
            const int ti = wid + 8 * s;
            acc[s] = (ti < NT) ? btab[ti * 4 + l4] : (f32x4){0.f,0.f,0.f,0.f};
        }

        // ---- GEMM: D = W^T-tiles x act, bf16x3 ----
        #pragma unroll
        for (int kt = 0; kt < KT; ++kt) {
            const short8 Ah = *(const short8*)&Abuf[cur][0][l15][kt * 32 + l4 * 8];
            const short8 Al = *(const short8*)&Abuf[cur][1][l15][kt * 32 + l4 * 8];
            #pragma unroll
            for (int s = 0; s < SLOTS; ++s) {
                if (wid + 8 * s < NT) {
                    acc[s] = __builtin_amdgcn_mfma_f32_16x16x32_bf16(Wh[s][kt], Ah, acc[s], 0, 0, 0);
                    acc[s] = __builtin_amdgcn_mfma_f32_16x16x32_bf16(Wl[s][kt], Ah, acc[s], 0, 0, 0);
                    acc[s] = __builtin_amdgcn_mfma_f32_16x16x32_bf16(Wh[s][kt], Al, acc[s], 0, 0, 0);
                }
            }
        }

        // ---- cell update: lane-local (unit = ti*4+l4, row = l15) ----
        #pragma unroll
        for (int s = 0; s < SLOTS; ++s) {
            const int ti = wid + 8 * s;
            if (ti < NT) {
                const float F  = sigmoidf_(acc[s][0]);
                const float I  = sigmoidf_(acc[s][1]);
                const float Gv = tanh_fast(acc[s][2]);
                const float O  = sigmoidf_(acc[s][3]);
                c_[s] = F * c_[s] + I * Gv;
                const float h = O * tanh_fast(c_[s]);
                hlast[s] = h;
                const int up = ti * 4 + l4;
                if (up < U) {
                    const unsigned short hh = bf16_rne(h);
                    const unsigned short hl = bf16_rne(h - bf16_to_f(hh));
                    Abuf[nxt][0][l15][up] = (short)hh;
                    Abuf[nxt][1][l15][up] = (short)hl;
                    if constexpr (SEQ)
                        Hpk[((size_t)(brow + l15) * T_SEQ + t) * U + up]
                            = (unsigned)hh | ((unsigned)hl << 16);
                }
            }
        }

        // ---- stage x(t+1) into next buffer ----
        if (dopre) {
            if constexpr (XF32) {
                const unsigned short h0 = bf16_rne(xv.x), h1 = bf16_rne(xv.y);
                Abuf[nxt][0][xrow][U + xj]     = (short)h0;
                Abuf[nxt][0][xrow][U + xj + 1] = (short)h1;
                Abuf[nxt][1][xrow][U + xj]     = (short)bf16_rne(xv.x - bf16_to_f(h0));
                Abuf[nxt][1][xrow][U + xj + 1] = (short)bf16_rne(xv.y - bf16_to_f(h1));
            } else {
                #pragma unroll
                for (int it = 0; it < XIT; ++it) if (xok[it]) {
                    Abuf[nxt][0][xwr[it]][U + xwc[it]] = (short)(xg[it] & 0xffffu);
                    Abuf[nxt][1][xwr[it]][U + xwc[it]] = (short)(xg[it] >> 16);
                }
            }
        }
        __syncthreads();
    }

    if constexpr (FINAL) {
        // dense head: OUT[row] = sum_u h[u][row]*Wd[u] + bd  (SLOTS == 1)
        const int up = wid * 4 + l4;
        float p = 0.0f;
        if (up < U) p = hlast[0] * Wd[up];
        p += __shfl_xor(p, 16, 64);
        p += __shfl_xor(p, 32, 64);
        if ((tid & 48) == 0) redu[wid][l15] = p;
        __syncthreads();
        if (tid < 16) {
            float a = bd[0];
            #pragma unroll
            for (int w2 = 0; w2 < 8; ++w2) a += redu[w2][tid];
            OUT[brow + tid] = a;
        }
    }
}

extern "C" void kernel_launch(void* const* d_in, const int* in_sizes, int n_in,
                              void* d_out, int out_size, void* d_ws, size_t ws_size,
                              hipStream_t stream)
{
    const float* x    = (const float*)d_in[0];
    const float* W0   = (const float*)d_in[1];
    const float* b0   = (const float*)d_in[2];
    const float* W1   = (const float*)d_in[3];
    const float* b1   = (const float*)d_in[4];
    const float* W2   = (const float*)d_in[5];
    const float* b2   = (const float*)d_in[6];
    const float* W3   = (const float*)d_in[7];
    const float* b3   = (const float*)d_in[8];
    const float* Wout = (const float*)d_in[9];
    const float* bout = (const float*)d_in[10];
    float* out = (float*)d_out;

    unsigned* H0pk = (unsigned*)d_ws;                      // 512*512*100 u32
    unsigned* H1pk = H0pk + (size_t)B_TOT * T_SEQ * 100;   // 512*512*80
    unsigned* H2pk = (unsigned*)d_ws;                      // reuses H0 slot

    const dim3 grid(B_TOT / 16);   // 32 blocks x 16 rows
    const dim3 blk(512);

    // <U, UP, FI, KT, SLOTS, XF32, SEQ, FINAL>
    hipLaunchKernelGGL((lstm_mfma<100, 100,  64, 6, 4, true,  true,  false>),
                       grid, blk, 0, stream,
                       x, nullptr, W0, b0, H0pk, nullptr, nullptr, nullptr);
    hipLaunchKernelGGL((lstm_mfma< 80,  80, 100, 6, 3, false, true,  false>),
                       grid, blk, 0, stream,
                       nullptr, H0pk, W1, b1, H1pk, nullptr, nullptr, nullptr);
    hipLaunchKernelGGL((lstm_mfma< 50,  52,  80, 5, 2, false, true,  false>),
                       grid, blk, 0, stream,
                       nullptr, H1pk, W2, b2, H2pk, nullptr, nullptr, nullptr);
    hipLaunchKernelGGL((lstm_mfma< 30,  32,  50, 3, 1, false, false, true >),
                       grid, blk, 0, stream,
                       nullptr, H2pk, W3, b3, nullptr, Wout, bout, out);
}